// Round 8
// baseline (191.738 us; speedup 1.0000x reference)
//
#include <hip/hip_runtime.h>

typedef _Float16 f16;
typedef f16 f16x8 __attribute__((ext_vector_type(8)));
typedef f16 f16x4 __attribute__((ext_vector_type(4)));
typedef f16 f16x2 __attribute__((ext_vector_type(2)));
typedef float f32x4 __attribute__((ext_vector_type(4)));
typedef float f32x16 __attribute__((ext_vector_type(16)));
typedef unsigned int u32;
typedef u32 u32x2 __attribute__((ext_vector_type(2)));
typedef u32 u32x4 __attribute__((ext_vector_type(4)));

#define MFMA16(a, b, c) __builtin_amdgcn_mfma_f32_16x16x32_f16(a, b, c, 0, 0, 0)
#define MFMA32(a, b, c) __builtin_amdgcn_mfma_f32_32x32x16_f16(a, b, c, 0, 0, 0)

#define BATCH 4
#define NHEADS 8
#define HDIM 64
#define SEQ 2048
#define DIN 512
#define DOUT 512
#define LOG2E 1.44269504f
#define C1 0.18033688f  // 0.125 * log2(e), folded into Q at qkv epilogue

__device__ __forceinline__ void gl_lds16(const void* g, const void* l) {
  __builtin_amdgcn_global_load_lds(
      (const __attribute__((address_space(1))) u32*)g,
      (__attribute__((address_space(3))) u32*)l, 16, 0, 0);
}

__device__ __forceinline__ float fexp2(float x) {
  float r;
  asm("v_exp_f32 %0, %1" : "=v"(r) : "v"(x));
  return r;
}

__device__ __forceinline__ u32 pk2u(float a, float b) {
  return __builtin_bit_cast(u32, __builtin_amdgcn_cvt_pkrtz(a, b));
}

__device__ __forceinline__ f16x2 pk2(float a, float b) {
  return __builtin_bit_cast(f16x2, __builtin_amdgcn_cvt_pkrtz(a, b));
}

__device__ __forceinline__ f16x4 pk4(float a, float b, float c, float d) {
  f16x2 u0 = pk2(a, b), u1 = pk2(c, d);
  f16x4 r;
  r[0] = u0[0]; r[1] = u0[1]; r[2] = u1[0]; r[3] = u1[1];
  return r;
}

// ---------------------------------------------------------------------------
// prep_w: transpose+cvt weights w[k][n] fp32 -> wT[n][k] f16.  (unchanged)
// ---------------------------------------------------------------------------
__global__ __launch_bounds__(256) void prep_w(
    const float* __restrict__ wq, const float* __restrict__ wk,
    const float* __restrict__ wv, f16* __restrict__ wT) {
  __shared__ float tile[64][65];
  const float* w = blockIdx.z == 0 ? wq : (blockIdx.z == 1 ? wk : wv);
  f16* out = wT + (size_t)blockIdx.z * DIN * DOUT;
  int k0 = blockIdx.x * 64, n0 = blockIdx.y * 64;
  int t = threadIdx.x;
  int c = t & 63, rb = t >> 6;
#pragma unroll
  for (int ph = 0; ph < 16; ++ph) {
    int r = ph * 4 + rb;
    tile[r][c] = w[(size_t)(k0 + r) * DOUT + n0 + c];
  }
  __syncthreads();
#pragma unroll
  for (int ph = 0; ph < 16; ++ph) {
    int n = ph * 4 + rb;
    out[(size_t)(n0 + n) * DIN + k0 + c] = (f16)tile[c][n];
  }
}

// ---------------------------------------------------------------------------
// qkv_gemm R15: kill the per-K-step vmcnt(0) drain (m97 drain-stall).
//  - B double-buffered (DMA path): LDS 16K As + 2x16K Bs = 48 KB -> still
//    3 blocks/CU (m132 occupancy cliff avoided; CT 32KB aliases As+Bs0).
//  - per K-step: A float4 loads issued FIRST (oldest in vmcnt order, pinned
//    by sched_barrier), then B(t+1) DMAs into buf^1, then A pack/write.
//    Wait vmcnt(4)+lgkmcnt(0) (in-order retirement => B(t)+A landed, B(t+1)
//    in flight) + raw s_barrier; compute; bare s_barrier.  No vmcnt(0) in
//    the loop -> B HBM latency hides under a full compute phase.
//  - compute bodies, epilogues, grid: R11 verbatim.
// ---------------------------------------------------------------------------
__global__ __launch_bounds__(256, 3) void qkv_gemm(
    const float* __restrict__ xq, const float* __restrict__ xk,
    const float* __restrict__ xv, const f16* __restrict__ wT,
    f16* __restrict__ Qo, f16* __restrict__ Ko, f16* __restrict__ Vt) {
  __shared__ __attribute__((aligned(16))) f16 smem[24576];  // 48 KB
  f16* As = smem;          // 128x64            (16 KB)
  f16* Bs = smem + 8192;   // 2 x 128x64 dbuf   (32 KB)
  f16* CT = smem;          // epilogue: 128x128 (aliases As+Bs0)

  int gemm = blockIdx.z;
  const float* x = gemm == 0 ? xq : (gemm == 1 ? xk : xv);
  const f16* wt = wT + (size_t)gemm * DIN * DOUT;
  int bx = blockIdx.x;
  int m0 = (bx & 63) * 128, n0 = (bx >> 6) * 128;
  int t = threadIdx.x, w = t >> 6, lane = t & 63;
  int lr = lane & 15, lq = lane >> 4;
  int wm = (w >> 1) * 64, wn = (w & 1) * 64;

  // A staging (fp32 -> f16 through regs): 16 threads/row, 8 row-phases.
  int tr = t >> 4, tc = t & 15;
  const float* xg = x + (size_t)(m0 + tr) * DIN + tc * 4;
  int aw[8];
#pragma unroll
  for (int ph = 0; ph < 8; ++ph) {
    int r = tr + 16 * ph;
    int phys = (tc >> 1) ^ (r & 7);
    aw[ph] = r * 64 + phys * 8 + (tc & 1) * 4;
  }

  // B staging via DMA: regions of 8 rows x 128B, XOR chunk swizzle.
  int srow = lane >> 3;
  int schunk = (lane & 7) ^ srow;
  const f16* gb[4];
  const f16* lbb[4];
#pragma unroll
  for (int j = 0; j < 4; ++j) {
    int br = w * 32 + j * 8;
    gb[j] = wt + (size_t)(n0 + br + srow) * DIN + schunk * 8;
    lbb[j] = &Bs[__builtin_amdgcn_readfirstlane(br * 64)];
  }
  int xo0 = ((0 * 4 + lq) ^ (lr & 7)) * 8;
  int xo1 = ((1 * 4 + lq) ^ (lr & 7)) * 8;

  f32x4 zero = {0.f, 0.f, 0.f, 0.f};
  f32x4 acc[4][4];
#pragma unroll
  for (int i = 0; i < 4; ++i)
#pragma unroll
    for (int j = 0; j < 4; ++j) acc[i][j] = zero;

  // prologue: issue B(0) DMAs into Bs0
#pragma unroll
  for (int j = 0; j < 4; ++j) gl_lds16(gb[j], lbb[j]);

  for (int k0 = 0; k0 < DIN; k0 += 64) {
    int p = (k0 >> 6) & 1;
    // ---- A loads first (oldest in vmcnt order)
    float4 a[8];
#pragma unroll
    for (int ph = 0; ph < 8; ++ph)
      a[ph] = *(const float4*)(xg + (size_t)ph * 16 * DIN + k0);
    __builtin_amdgcn_sched_barrier(0);
    // ---- issue B(t+1) DMAs into buf^1 (read-done via trailing barrier t-1)
    if (k0 + 64 < DIN) {
#pragma unroll
      for (int j = 0; j < 4; ++j)
        gl_lds16(gb[j] + k0 + 64, lbb[j] + ((p ^ 1) * 8192));
    }
    __builtin_amdgcn_sched_barrier(0);
    // ---- pack/write A (compiler waits per a[ph]; never waits B(t+1))
#pragma unroll
    for (int ph = 0; ph < 8; ++ph)
      *(f16x4*)&As[aw[ph]] = pk4(a[ph].x, a[ph].y, a[ph].z, a[ph].w);
    // B(t) landed (in-order: older than A loads), A writes visible:
    asm volatile("s_waitcnt vmcnt(4) lgkmcnt(0)" ::: "memory");
    __builtin_amdgcn_sched_barrier(0);
    __builtin_amdgcn_s_barrier();
    __builtin_amdgcn_sched_barrier(0);

    const f16* Bp = Bs + p * 8192;
#pragma unroll
    for (int c = 0; c < 2; ++c) {
      int xo = c ? xo1 : xo0;
      f16x8 xf[4], wf[4];
#pragma unroll
      for (int i = 0; i < 4; ++i)
        xf[i] = *(const f16x8*)&As[(wm + i * 16 + lr) * 64 + xo];
#pragma unroll
      for (int i = 0; i < 4; ++i)
        wf[i] = *(const f16x8*)&Bp[(wn + i * 16 + lr) * 64 + xo];
      if (gemm == 2) {
#pragma unroll
        for (int i = 0; i < 4; ++i)
#pragma unroll
          for (int j = 0; j < 4; ++j)
            acc[i][j] = MFMA16(xf[i], wf[j], acc[i][j]);
      } else {
#pragma unroll
        for (int i = 0; i < 4; ++i)
#pragma unroll
          for (int j = 0; j < 4; ++j)
            acc[i][j] = MFMA16(wf[i], xf[j], acc[i][j]);
      }
    }
    // reads of As/Bs[p] done before next iter overwrites / epilogue aliases
    __builtin_amdgcn_sched_barrier(0);
    __builtin_amdgcn_s_barrier();
    __builtin_amdgcn_sched_barrier(0);
  }

  int b_ = m0 >> 11;
  int sl = m0 & 2047;

  if (gemm == 2) {
#pragma unroll
    for (int i = 0; i < 4; ++i) {
#pragma unroll
      for (int j = 0; j < 4; ++j) {
        int d = wn + j * 16 + lr;
        int lc = (wm >> 3) + i * 2 + (lq >> 1);
        int phys = lc ^ lr;
        *(f16x4*)&CT[d * 128 + phys * 8 + (lq & 1) * 4] =
            pk4(acc[i][j][0], acc[i][j][1], acc[i][j][2], acc[i][j][3]);
      }
    }
    __syncthreads();
    int tid16 = t & 15;
#pragma unroll
    for (int ph = 0; ph < 8; ++ph) {
      int d = ph * 16 + (t >> 4);
      int phys = tid16 ^ (d & 15);
      f16x8 vv = *(const f16x8*)&CT[d * 128 + phys * 8];
      int hgl = (n0 + d) >> 6, dd = (n0 + d) & 63;
      *(f16x8*)&Vt[(((size_t)b_ * NHEADS + hgl) * HDIM + dd) * SEQ + sl +
                   tid16 * 8] = vv;
    }
  } else {
    f16* O = gemm == 0 ? Qo : Ko;
    float sc = gemm == 0 ? C1 : 1.0f;
#pragma unroll
    for (int i = 0; i < 4; ++i) {
#pragma unroll
      for (int j = 0; j < 4; ++j) {
        int s = wm + j * 16 + lr;
        int lc = (wn >> 3) + i * 2 + (lq >> 1);
        int phys = lc ^ lr;
        *(f16x4*)&CT[s * 128 + phys * 8 + (lq & 1) * 4] =
            pk4(acc[i][j][0] * sc, acc[i][j][1] * sc, acc[i][j][2] * sc,
                acc[i][j][3] * sc);
      }
    }
    __syncthreads();
    int tid8 = t & 7;
    int hh = (t >> 3) & 1;
#pragma unroll
    for (int ph = 0; ph < 8; ++ph) {
      int s = ph * 16 + (t >> 4);
      int lc = hh * 8 + tid8;
      int phys = lc ^ (s & 15);
      f16x8 vv = *(const f16x8*)&CT[s * 128 + phys * 8];
      int hgl = (n0 >> 6) + hh;
      *(f16x8*)&O[(((size_t)b_ * NHEADS + hgl) * SEQ + sl + s) * HDIM +
                  tid8 * 8] = vv;
    }
  }
}

// ---------------------------------------------------------------------------
// flash_attn R14: FROZEN (control for this round's qkv attribution).
// ---------------------------------------------------------------------------
__global__ __launch_bounds__(256, 2) void flash_attn(
    const f16* __restrict__ Q, const f16* __restrict__ K,
    const f16* __restrict__ Vt, const float* __restrict__ mask,
    float* __restrict__ out) {
  __shared__ __attribute__((aligned(16))) f16 Ks[2 * 128 * 64];  // 32 KB
  __shared__ __attribute__((aligned(16))) f16 Vs[2 * 64 * 128];  // 32 KB
  __shared__ __attribute__((aligned(16))) float Ms[SEQ];         // 8 KB

  int bh = blockIdx.x, q0 = blockIdx.y * 128;
  int b = bh >> 3, h = bh & 7;
  int t = threadIdx.x, w = t >> 6, lane = t & 63;  // w in 0..3
  int l5 = lane & 31, hf = lane >> 5;

  const f16* Qg = Q + (size_t)bh * SEQ * HDIM;
  const f16* Kg = K + (size_t)bh * SEQ * HDIM;
  const f16* Vg = Vt + (size_t)bh * HDIM * SEQ;
  const float* mg = mask + (size_t)b * SEQ;

  // ---- staging pointers: K 4 regions of 8 rows x 128B; V 4 regions of 4x256B
  int krow = lane >> 3;
  int kchunk = (lane & 7) ^ krow;
  const f16* gk[4];
  const f16* gv[4];
  const f16* lk[4];
  const f16* lv[4];
#pragma unroll
  for (int j = 0; j < 4; ++j) {
    int kbr = w * 32 + j * 8;
    gk[j] = Kg + (size_t)(kbr + krow) * HDIM + kchunk * 8;
    lk[j] = &Ks[__builtin_amdgcn_readfirstlane(kbr * 64)];
    int vbr = w * 16 + j * 4;
    int lq = lane >> 4;
    int vchunk = (lane & 15) ^ ((vbr + lq) & 15);
    gv[j] = Vg + (size_t)(vbr + lq) * SEQ + vchunk * 8;
    lv[j] = &Vs[__builtin_amdgcn_readfirstlane(vbr * 128)];
  }

  // ---- prologue: stage mask + K0 + V0 into buf0 (DMA), then Q frags
  {
    int c0 = w * 512;  // 512 floats per wave, two 1KB DMAs
    gl_lds16(mg + c0 + lane * 4, &Ms[__builtin_amdgcn_readfirstlane(c0)]);
    gl_lds16(mg + c0 + 256 + lane * 4,
             &Ms[__builtin_amdgcn_readfirstlane(c0 + 256)]);
  }
#pragma unroll
  for (int j = 0; j < 4; ++j) {
    gl_lds16(gk[j], lk[j]);
    gl_lds16(gv[j], lv[j]);
  }

  // Q fragments (B-operand, rows q = q0 + w*32 + l5): qf[ds] covers
  // d = ds*16 + hf*8 + j
  f16x8 qf[4];
#pragma unroll
  for (int ds = 0; ds < 4; ++ds)
    qf[ds] = *(const f16x8*)(Qg + (size_t)(q0 + w * 32 + l5) * HDIM + ds * 16 +
                             hf * 8);

  const f32x16 Z = {0.f, 0.f, 0.f, 0.f, 0.f, 0.f, 0.f, 0.f,
                    0.f, 0.f, 0.f, 0.f, 0.f, 0.f, 0.f, 0.f};
  f32x16 acc[2][2];  // [dt][ks-parity] -> 4 independent MFMA chains
#pragma unroll
  for (int dt = 0; dt < 2; ++dt)
#pragma unroll
    for (int par = 0; par < 2; ++par) acc[dt][par] = Z;
  float lsum = 0.f;

  asm volatile("s_waitcnt vmcnt(0)" ::: "memory");
  __builtin_amdgcn_sched_barrier(0);
  __builtin_amdgcn_s_barrier();
  __builtin_amdgcn_sched_barrier(0);

#define QKT(nt, sv)                                                          \
  {                                                                          \
    __builtin_amdgcn_s_setprio(1);                                           \
    f16x8 kf0 = *(const f16x8*)&Kb[((nt)*32 + l5) * 64 +                     \
                                   (((0 + hf) ^ (l5 & 7)) * 8)];             \
    sv = MFMA32(kf0, qf[0], Z);                                              \
    _Pragma("unroll") for (int ds = 1; ds < 4; ++ds) {                       \
      f16x8 kf = *(const f16x8*)&Kb[((nt)*32 + l5) * 64 +                    \
                                    (((ds * 2 + hf) ^ (l5 & 7)) * 8)];       \
      sv = MFMA32(kf, qf[ds], sv);                                           \
    }                                                                        \
    __builtin_amdgcn_s_setprio(0);                                           \
  }

#define SM(nt, sv)                                                           \
  _Pragma("unroll") for (int run = 0; run < 4; ++run) {                      \
    float4 mk = *(const float4*)&Ms[k0 + (nt)*32 + run * 8 + 4 * hf];        \
    float p0 = fexp2(fmaf(mk.x, LOG2E, sv[run * 4 + 0]));                    \
    float p1 = fexp2(fmaf(mk.y, LOG2E, sv[run * 4 + 1]));                    \
    float p2 = fexp2(fmaf(mk.z, LOG2E, sv[run * 4 + 2]));                    \
    float p3 = fexp2(fmaf(mk.w, LOG2E, sv[run * 4 + 3]));                    \
    lsum += (p0 + p1) + (p2 + p3);                                           \
    pk_[nt][run][0] = pk2u(p0, p1);                                          \
    pk_[nt][run][1] = pk2u(p2, p3);                                          \
  }

  for (int it = 0; it < 16; ++it) {
    int p = it & 1;
    int k0 = it * 128;
    const f16* Kb = &Ks[p * 8192];
    const f16* Vb = &Vs[p * 8192];

    // ---- issue prefetch of tile t+1 into buf^1 (read-done via last barrier)
    if (it < 15) {
      int pn = p ^ 1;
#pragma unroll
      for (int j = 0; j < 4; ++j) {
        gl_lds16(gk[j] + (size_t)(k0 + 128) * HDIM, lk[j] + pn * 8192);
        gl_lds16(gv[j] + k0 + 128, lv[j] + pn * 8192);
      }
    }

    u32 pk_[4][4][2];  // [nt][g=r>>2][word]

    // ---- S^T = K Q^T with nt-skew: QKT(nt+1) issued before softmax(nt)
    {
      f32x16 sA, sB;
      QKT(0, sA);
      QKT(1, sB);
      SM(0, sA);
      QKT(2, sA);
      SM(1, sB);
      QKT(3, sB);
      SM(2, sA);
      SM(3, sB);
    }

    // ---- O += P V  (ap assembled in-register via permlane32_swap);
    //      acc chains split by ks parity (4 independent chains)
    __builtin_amdgcn_s_setprio(1);
#pragma unroll
    for (int ks = 0; ks < 8; ++ks) {
      const int nt = ks >> 1;
      const int ge = 2 * (ks & 1);      // g for hf=0 lanes
      const int go = 2 * (ks & 1) + 1;  // g for hf=1 lanes
      u32x2 r0 = __builtin_amdgcn_permlane32_swap(pk_[nt][ge][0],
                                                  pk_[nt][go][0], false, false);
      u32x2 r1 = __builtin_amdgcn_permlane32_swap(pk_[nt][ge][1],
                                                  pk_[nt][go][1], false, false);
      u32x4 apw = {r0[0], r1[0], r0[1], r1[1]};
      f16x8 ap = __builtin_bit_cast(f16x8, apw);
#pragma unroll
      for (int dt = 0; dt < 2; ++dt) {
        f16x8 bv = *(const f16x8*)&Vb[(dt * 32 + l5) * 128 +
                                      (((ks * 2 + hf) ^ (l5 & 15)) * 8)];
        acc[dt][ks & 1] = MFMA32(ap, bv, acc[dt][ks & 1]);
      }
    }
    __builtin_amdgcn_s_setprio(0);

    // ---- single end-of-iter sync: own DMAs (issued at iter start) landed;
    // barrier => all waves' DMAs landed + all reads of buf done.
    asm volatile("s_waitcnt vmcnt(0)" ::: "memory");
    __builtin_amdgcn_sched_barrier(0);
    __builtin_amdgcn_s_barrier();
    __builtin_amdgcn_sched_barrier(0);
  }
#undef QKT
#undef SM

  // ---- epilogue: cross-half l sum, redistribute inv via Ms[0:128) scratch
  // (safe: last-iter mask reads touch Ms[1920:2048) only; region is
  // wave-private so no barrier needed)
  float l = lsum + __shfl_xor(lsum, 32);
  float inv = 1.f / l;
  Ms[w * 32 + l5] = inv;  // lanes l5 / l5+32 write same value
  asm volatile("s_waitcnt lgkmcnt(0)" ::: "memory");
  __builtin_amdgcn_sched_barrier(0);
  float ivq[16];
#pragma unroll
  for (int r = 0; r < 16; ++r)
    ivq[r] = Ms[w * 32 + (r & 3) + 8 * (r >> 2) + 4 * hf];

#pragma unroll
  for (int dt = 0; dt < 2; ++dt) {
#pragma unroll
    for (int r = 0; r < 16; ++r) {
      int q = q0 + w * 32 + (r & 3) + 8 * (r >> 2) + 4 * hf;
      int d = h * HDIM + dt * 32 + l5;
      out[((size_t)b * SEQ + q) * DOUT + d] =
          (acc[dt][0][r] + acc[dt][1][r]) * ivq[r];
    }
  }
}

// ---------------------------------------------------------------------------
extern "C" void kernel_launch(void* const* d_in, const int* in_sizes, int n_in,
                              void* d_out, int out_size, void* d_ws,
                              size_t ws_size, hipStream_t stream) {
  const float* key = (const float*)d_in[0];
  const float* key_mask = (const float*)d_in[1];
  const float* query = (const float*)d_in[2];
  const float* value = (const float*)d_in[3];
  const float* wq = (const float*)d_in[4];
  const float* wk = (const float*)d_in[5];
  const float* wv = (const float*)d_in[6];
  float* out = (float*)d_out;

  char* ws = (char*)d_ws;
  f16* Qws = (f16*)(ws);              //  8.39 MB
  f16* Kws = (f16*)(ws + 8388608);    //  8.39 MB
  f16* Vtws = (f16*)(ws + 16777216);  //  8.39 MB
  f16* wT = (f16*)(ws + 25165824);    //  1.57 MB (total ~26.7 MB)

  prep_w<<<dim3(8, 8, 3), 256, 0, stream>>>(wq, wk, wv, wT);
  qkv_gemm<<<dim3(256, 1, 3), 256, 0, stream>>>(query, key, value, wT, Qws,
                                                Kws, Vtws);
  flash_attn<<<dim3(32, 16), 256, 0, stream>>>(Qws, Kws, Vtws, key_mask, out);
}

// Round 9
// 178.888 us; speedup vs baseline: 1.0718x; 1.0718x over previous
//
#include <hip/hip_runtime.h>

typedef _Float16 f16;
typedef f16 f16x8 __attribute__((ext_vector_type(8)));
typedef f16 f16x4 __attribute__((ext_vector_type(4)));
typedef f16 f16x2 __attribute__((ext_vector_type(2)));
typedef float f32x4 __attribute__((ext_vector_type(4)));
typedef float f32x16 __attribute__((ext_vector_type(16)));
typedef unsigned int u32;
typedef u32 u32x2 __attribute__((ext_vector_type(2)));
typedef u32 u32x4 __attribute__((ext_vector_type(4)));

#define MFMA16(a, b, c) __builtin_amdgcn_mfma_f32_16x16x32_f16(a, b, c, 0, 0, 0)
#define MFMA32(a, b, c) __builtin_amdgcn_mfma_f32_32x32x16_f16(a, b, c, 0, 0, 0)

#define BATCH 4
#define NHEADS 8
#define HDIM 64
#define SEQ 2048
#define DIN 512
#define DOUT 512
#define LOG2E 1.44269504f
#define C1 0.18033688f  // 0.125 * log2(e), folded into Q at qkv epilogue

__device__ __forceinline__ void gl_lds16(const void* g, const void* l) {
  __builtin_amdgcn_global_load_lds(
      (const __attribute__((address_space(1))) u32*)g,
      (__attribute__((address_space(3))) u32*)l, 16, 0, 0);
}

__device__ __forceinline__ float fexp2(float x) {
  float r;
  asm("v_exp_f32 %0, %1" : "=v"(r) : "v"(x));
  return r;
}

__device__ __forceinline__ u32 pk2u(float a, float b) {
  return __builtin_bit_cast(u32, __builtin_amdgcn_cvt_pkrtz(a, b));
}

__device__ __forceinline__ f16x2 pk2(float a, float b) {
  return __builtin_bit_cast(f16x2, __builtin_amdgcn_cvt_pkrtz(a, b));
}

__device__ __forceinline__ f16x4 pk4(float a, float b, float c, float d) {
  f16x2 u0 = pk2(a, b), u1 = pk2(c, d);
  f16x4 r;
  r[0] = u0[0]; r[1] = u0[1]; r[2] = u1[0]; r[3] = u1[1];
  return r;
}

// ---------------------------------------------------------------------------
// prep_w: transpose+cvt weights w[k][n] fp32 -> wT[n][k] f16.  (unchanged)
// ---------------------------------------------------------------------------
__global__ __launch_bounds__(256) void prep_w(
    const float* __restrict__ wq, const float* __restrict__ wk,
    const float* __restrict__ wv, f16* __restrict__ wT) {
  __shared__ float tile[64][65];
  const float* w = blockIdx.z == 0 ? wq : (blockIdx.z == 1 ? wk : wv);
  f16* out = wT + (size_t)blockIdx.z * DIN * DOUT;
  int k0 = blockIdx.x * 64, n0 = blockIdx.y * 64;
  int t = threadIdx.x;
  int c = t & 63, rb = t >> 6;
#pragma unroll
  for (int ph = 0; ph < 16; ++ph) {
    int r = ph * 4 + rb;
    tile[r][c] = w[(size_t)(k0 + r) * DOUT + n0 + c];
  }
  __syncthreads();
#pragma unroll
  for (int ph = 0; ph < 16; ++ph) {
    int n = ph * 4 + rb;
    out[(size_t)(n0 + n) * DIN + k0 + c] = (f16)tile[c][n];
  }
}

// ---------------------------------------------------------------------------
// qkv_gemm R16: B double-buffer WITHOUT R15's spill bug.
//  - R11's fused per-ph A load->pack kept verbatim (no 8xfloat4 live range,
//    no forced sched_barriers -> no spill; R15's WRITE_SIZE 81MB was spill).
//  - Per k-step: {A load+pack (compiler's own vmcnt waits for A, issued
//    AFTER B(t), imply B(t) landed — in-order retirement); issue B(t+1)
//    into buf^1; lgkmcnt(0) (flush A ds_writes); s_barrier; compute Bs[p];
//    s_barrier}.  NO vmcnt drain anywhere in the loop: B latency hides
//    under the next iteration's A-load+pack phase.
//  - LDS 48 KB (As 16K + Bs dbuf 32K) -> 3 blocks/CU kept; CT aliases
//    As+Bs0 (last compute reads Bs1; safe after trailing barrier).
// ---------------------------------------------------------------------------
__global__ __launch_bounds__(256, 3) void qkv_gemm(
    const float* __restrict__ xq, const float* __restrict__ xk,
    const float* __restrict__ xv, const f16* __restrict__ wT,
    f16* __restrict__ Qo, f16* __restrict__ Ko, f16* __restrict__ Vt) {
  __shared__ __attribute__((aligned(16))) f16 smem[24576];  // 48 KB
  f16* As = smem;          // 128x64            (16 KB)
  f16* Bs = smem + 8192;   // 2 x 128x64 dbuf   (32 KB)
  f16* CT = smem;          // epilogue: 128x128 (aliases As+Bs0)

  int gemm = blockIdx.z;
  const float* x = gemm == 0 ? xq : (gemm == 1 ? xk : xv);
  const f16* wt = wT + (size_t)gemm * DIN * DOUT;
  int bx = blockIdx.x;
  int m0 = (bx & 63) * 128, n0 = (bx >> 6) * 128;
  int t = threadIdx.x, w = t >> 6, lane = t & 63;
  int lr = lane & 15, lq = lane >> 4;
  int wm = (w >> 1) * 64, wn = (w & 1) * 64;

  // A staging (fp32 -> f16 through regs): 16 threads/row, 8 row-phases.
  int tr = t >> 4, tc = t & 15;
  const float* xg = x + (size_t)(m0 + tr) * DIN + tc * 4;
  int aw[8];
#pragma unroll
  for (int ph = 0; ph < 8; ++ph) {
    int r = tr + 16 * ph;
    int phys = (tc >> 1) ^ (r & 7);
    aw[ph] = r * 64 + phys * 8 + (tc & 1) * 4;
  }

  // B staging via DMA: regions of 8 rows x 128B, XOR chunk swizzle.
  int srow = lane >> 3;
  int schunk = (lane & 7) ^ srow;
  const f16* gb[4];
  f16* lbb[4];
#pragma unroll
  for (int j = 0; j < 4; ++j) {
    int br = w * 32 + j * 8;
    gb[j] = wt + (size_t)(n0 + br + srow) * DIN + schunk * 8;
    lbb[j] = &Bs[__builtin_amdgcn_readfirstlane(br * 64)];
  }
  int xo0 = ((0 * 4 + lq) ^ (lr & 7)) * 8;
  int xo1 = ((1 * 4 + lq) ^ (lr & 7)) * 8;

  f32x4 zero = {0.f, 0.f, 0.f, 0.f};
  f32x4 acc[4][4];
#pragma unroll
  for (int i = 0; i < 4; ++i)
#pragma unroll
    for (int j = 0; j < 4; ++j) acc[i][j] = zero;

  // prologue: issue B(0) DMAs into Bs0
#pragma unroll
  for (int j = 0; j < 4; ++j) gl_lds16(gb[j], lbb[j]);

  for (int k0 = 0; k0 < DIN; k0 += 64) {
    int p = (k0 >> 6) & 1;
    // ---- A load+pack, R11-fused form (compiler inserts per-load vmcnt
    // waits; those waits retire the older B(t) DMAs too — in-order).
#pragma unroll
    for (int ph = 0; ph < 8; ++ph) {
      float4 a = *(const float4*)(xg + (size_t)ph * 16 * DIN + k0);
      *(f16x4*)&As[aw[ph]] = pk4(a.x, a.y, a.z, a.w);
    }
    // ---- issue B(t+1) into buf^1 (that buf's readers finished at the
    // trailing barrier of iteration t-1).
    if (k0 + 64 < DIN) {
#pragma unroll
      for (int j = 0; j < 4; ++j)
        gl_lds16(gb[j] + k0 + 64, lbb[j] + ((p ^ 1) * 8192));
    }
    // ---- my A ds_writes visible; B(t) proven landed via A-load waits.
    asm volatile("s_waitcnt lgkmcnt(0)" ::: "memory");
    __builtin_amdgcn_sched_barrier(0);
    __builtin_amdgcn_s_barrier();
    __builtin_amdgcn_sched_barrier(0);

    const f16* Bp = Bs + p * 8192;
#pragma unroll
    for (int c = 0; c < 2; ++c) {
      int xo = c ? xo1 : xo0;
      f16x8 xf[4], wf[4];
#pragma unroll
      for (int i = 0; i < 4; ++i)
        xf[i] = *(const f16x8*)&As[(wm + i * 16 + lr) * 64 + xo];
#pragma unroll
      for (int i = 0; i < 4; ++i)
        wf[i] = *(const f16x8*)&Bp[(wn + i * 16 + lr) * 64 + xo];
      if (gemm == 2) {
#pragma unroll
        for (int i = 0; i < 4; ++i)
#pragma unroll
          for (int j = 0; j < 4; ++j)
            acc[i][j] = MFMA16(xf[i], wf[j], acc[i][j]);
      } else {
#pragma unroll
        for (int i = 0; i < 4; ++i)
#pragma unroll
          for (int j = 0; j < 4; ++j)
            acc[i][j] = MFMA16(wf[i], xf[j], acc[i][j]);
      }
    }
    // reads of As/Bs[p] done before next iter's packs / epilogue CT.
    __builtin_amdgcn_sched_barrier(0);
    __builtin_amdgcn_s_barrier();
    __builtin_amdgcn_sched_barrier(0);
  }

  int b_ = m0 >> 11;
  int sl = m0 & 2047;

  if (gemm == 2) {
#pragma unroll
    for (int i = 0; i < 4; ++i) {
#pragma unroll
      for (int j = 0; j < 4; ++j) {
        int d = wn + j * 16 + lr;
        int lc = (wm >> 3) + i * 2 + (lq >> 1);
        int phys = lc ^ lr;
        *(f16x4*)&CT[d * 128 + phys * 8 + (lq & 1) * 4] =
            pk4(acc[i][j][0], acc[i][j][1], acc[i][j][2], acc[i][j][3]);
      }
    }
    __syncthreads();
    int tid16 = t & 15;
#pragma unroll
    for (int ph = 0; ph < 8; ++ph) {
      int d = ph * 16 + (t >> 4);
      int phys = tid16 ^ (d & 15);
      f16x8 vv = *(const f16x8*)&CT[d * 128 + phys * 8];
      int hgl = (n0 + d) >> 6, dd = (n0 + d) & 63;
      *(f16x8*)&Vt[(((size_t)b_ * NHEADS + hgl) * HDIM + dd) * SEQ + sl +
                   tid16 * 8] = vv;
    }
  } else {
    f16* O = gemm == 0 ? Qo : Ko;
    float sc = gemm == 0 ? C1 : 1.0f;
#pragma unroll
    for (int i = 0; i < 4; ++i) {
#pragma unroll
      for (int j = 0; j < 4; ++j) {
        int s = wm + j * 16 + lr;
        int lc = (wn >> 3) + i * 2 + (lq >> 1);
        int phys = lc ^ lr;
        *(f16x4*)&CT[s * 128 + phys * 8 + (lq & 1) * 4] =
            pk4(acc[i][j][0] * sc, acc[i][j][1] * sc, acc[i][j][2] * sc,
                acc[i][j][3] * sc);
      }
    }
    __syncthreads();
    int tid8 = t & 7;
    int hh = (t >> 3) & 1;
#pragma unroll
    for (int ph = 0; ph < 8; ++ph) {
      int s = ph * 16 + (t >> 4);
      int lc = hh * 8 + tid8;
      int phys = lc ^ (s & 15);
      f16x8 vv = *(const f16x8*)&CT[s * 128 + phys * 8];
      int hgl = (n0 >> 6) + hh;
      *(f16x8*)&O[(((size_t)b_ * NHEADS + hgl) * SEQ + sl + s) * HDIM +
                  tid8 * 8] = vv;
    }
  }
}

// ---------------------------------------------------------------------------
// flash_attn R14: FROZEN (control).
// ---------------------------------------------------------------------------
__global__ __launch_bounds__(256, 2) void flash_attn(
    const f16* __restrict__ Q, const f16* __restrict__ K,
    const f16* __restrict__ Vt, const float* __restrict__ mask,
    float* __restrict__ out) {
  __shared__ __attribute__((aligned(16))) f16 Ks[2 * 128 * 64];  // 32 KB
  __shared__ __attribute__((aligned(16))) f16 Vs[2 * 64 * 128];  // 32 KB
  __shared__ __attribute__((aligned(16))) float Ms[SEQ];         // 8 KB

  int bh = blockIdx.x, q0 = blockIdx.y * 128;
  int b = bh >> 3, h = bh & 7;
  int t = threadIdx.x, w = t >> 6, lane = t & 63;  // w in 0..3
  int l5 = lane & 31, hf = lane >> 5;

  const f16* Qg = Q + (size_t)bh * SEQ * HDIM;
  const f16* Kg = K + (size_t)bh * SEQ * HDIM;
  const f16* Vg = Vt + (size_t)bh * HDIM * SEQ;
  const float* mg = mask + (size_t)b * SEQ;

  // ---- staging pointers: K 4 regions of 8 rows x 128B; V 4 regions of 4x256B
  int krow = lane >> 3;
  int kchunk = (lane & 7) ^ krow;
  const f16* gk[4];
  const f16* gv[4];
  const f16* lk[4];
  const f16* lv[4];
#pragma unroll
  for (int j = 0; j < 4; ++j) {
    int kbr = w * 32 + j * 8;
    gk[j] = Kg + (size_t)(kbr + krow) * HDIM + kchunk * 8;
    lk[j] = &Ks[__builtin_amdgcn_readfirstlane(kbr * 64)];
    int vbr = w * 16 + j * 4;
    int lq = lane >> 4;
    int vchunk = (lane & 15) ^ ((vbr + lq) & 15);
    gv[j] = Vg + (size_t)(vbr + lq) * SEQ + vchunk * 8;
    lv[j] = &Vs[__builtin_amdgcn_readfirstlane(vbr * 128)];
  }

  // ---- prologue: stage mask + K0 + V0 into buf0 (DMA), then Q frags
  {
    int c0 = w * 512;  // 512 floats per wave, two 1KB DMAs
    gl_lds16(mg + c0 + lane * 4, &Ms[__builtin_amdgcn_readfirstlane(c0)]);
    gl_lds16(mg + c0 + 256 + lane * 4,
             &Ms[__builtin_amdgcn_readfirstlane(c0 + 256)]);
  }
#pragma unroll
  for (int j = 0; j < 4; ++j) {
    gl_lds16(gk[j], lk[j]);
    gl_lds16(gv[j], lv[j]);
  }

  // Q fragments (B-operand, rows q = q0 + w*32 + l5): qf[ds] covers
  // d = ds*16 + hf*8 + j
  f16x8 qf[4];
#pragma unroll
  for (int ds = 0; ds < 4; ++ds)
    qf[ds] = *(const f16x8*)(Qg + (size_t)(q0 + w * 32 + l5) * HDIM + ds * 16 +
                             hf * 8);

  const f32x16 Z = {0.f, 0.f, 0.f, 0.f, 0.f, 0.f, 0.f, 0.f,
                    0.f, 0.f, 0.f, 0.f, 0.f, 0.f, 0.f, 0.f};
  f32x16 acc[2][2];  // [dt][ks-parity] -> 4 independent MFMA chains
#pragma unroll
  for (int dt = 0; dt < 2; ++dt)
#pragma unroll
    for (int par = 0; par < 2; ++par) acc[dt][par] = Z;
  float lsum = 0.f;

  asm volatile("s_waitcnt vmcnt(0)" ::: "memory");
  __builtin_amdgcn_sched_barrier(0);
  __builtin_amdgcn_s_barrier();
  __builtin_amdgcn_sched_barrier(0);

#define QKT(nt, sv)                                                          \
  {                                                                          \
    __builtin_amdgcn_s_setprio(1);                                           \
    f16x8 kf0 = *(const f16x8*)&Kb[((nt)*32 + l5) * 64 +                     \
                                   (((0 + hf) ^ (l5 & 7)) * 8)];             \
    sv = MFMA32(kf0, qf[0], Z);                                              \
    _Pragma("unroll") for (int ds = 1; ds < 4; ++ds) {                       \
      f16x8 kf = *(const f16x8*)&Kb[((nt)*32 + l5) * 64 +                    \
                                    (((ds * 2 + hf) ^ (l5 & 7)) * 8)];       \
      sv = MFMA32(kf, qf[ds], sv);                                           \
    }                                                                        \
    __builtin_amdgcn_s_setprio(0);                                           \
  }

#define SM(nt, sv)                                                           \
  _Pragma("unroll") for (int run = 0; run < 4; ++run) {                      \
    float4 mk = *(const float4*)&Ms[k0 + (nt)*32 + run * 8 + 4 * hf];        \
    float p0 = fexp2(fmaf(mk.x, LOG2E, sv[run * 4 + 0]));                    \
    float p1 = fexp2(fmaf(mk.y, LOG2E, sv[run * 4 + 1]));                    \
    float p2 = fexp2(fmaf(mk.z, LOG2E, sv[run * 4 + 2]));                    \
    float p3 = fexp2(fmaf(mk.w, LOG2E, sv[run * 4 + 3]));                    \
    lsum += (p0 + p1) + (p2 + p3);                                           \
    pk_[nt][run][0] = pk2u(p0, p1);                                          \
    pk_[nt][run][1] = pk2u(p2, p3);                                          \
  }

  for (int it = 0; it < 16; ++it) {
    int p = it & 1;
    int k0 = it * 128;
    const f16* Kb = &Ks[p * 8192];
    const f16* Vb = &Vs[p * 8192];

    // ---- issue prefetch of tile t+1 into buf^1 (read-done via last barrier)
    if (it < 15) {
      int pn = p ^ 1;
#pragma unroll
      for (int j = 0; j < 4; ++j) {
        gl_lds16(gk[j] + (size_t)(k0 + 128) * HDIM, lk[j] + pn * 8192);
        gl_lds16(gv[j] + k0 + 128, lv[j] + pn * 8192);
      }
    }

    u32 pk_[4][4][2];  // [nt][g=r>>2][word]

    // ---- S^T = K Q^T with nt-skew: QKT(nt+1) issued before softmax(nt)
    {
      f32x16 sA, sB;
      QKT(0, sA);
      QKT(1, sB);
      SM(0, sA);
      QKT(2, sA);
      SM(1, sB);
      QKT(3, sB);
      SM(2, sA);
      SM(3, sB);
    }

    // ---- O += P V  (ap assembled in-register via permlane32_swap);
    //      acc chains split by ks parity (4 independent chains)
    __builtin_amdgcn_s_setprio(1);
#pragma unroll
    for (int ks = 0; ks < 8; ++ks) {
      const int nt = ks >> 1;
      const int ge = 2 * (ks & 1);      // g for hf=0 lanes
      const int go = 2 * (ks & 1) + 1;  // g for hf=1 lanes
      u32x2 r0 = __builtin_amdgcn_permlane32_swap(pk_[nt][ge][0],
                                                  pk_[nt][go][0], false, false);
      u32x2 r1 = __builtin_amdgcn_permlane32_swap(pk_[nt][ge][1],
                                                  pk_[nt][go][1], false, false);
      u32x4 apw = {r0[0], r1[0], r0[1], r1[1]};
      f16x8 ap = __builtin_bit_cast(f16x8, apw);
#pragma unroll
      for (int dt = 0; dt < 2; ++dt) {
        f16x8 bv = *(const f16x8*)&Vb[(dt * 32 + l5) * 128 +
                                      (((ks * 2 + hf) ^ (l5 & 15)) * 8)];
        acc[dt][ks & 1] = MFMA32(ap, bv, acc[dt][ks & 1]);
      }
    }
    __builtin_amdgcn_s_setprio(0);

    // ---- single end-of-iter sync: own DMAs (issued at iter start) landed;
    // barrier => all waves' DMAs landed + all reads of buf done.
    asm volatile("s_waitcnt vmcnt(0)" ::: "memory");
    __builtin_amdgcn_sched_barrier(0);
    __builtin_amdgcn_s_barrier();
    __builtin_amdgcn_sched_barrier(0);
  }
#undef QKT
#undef SM

  // ---- epilogue: cross-half l sum, redistribute inv via Ms[0:128) scratch
  // (safe: last-iter mask reads touch Ms[1920:2048) only; region is
  // wave-private so no barrier needed)
  float l = lsum + __shfl_xor(lsum, 32);
  float inv = 1.f / l;
  Ms[w * 32 + l5] = inv;  // lanes l5 / l5+32 write same value
  asm volatile("s_waitcnt lgkmcnt(0)" ::: "memory");
  __builtin_amdgcn_sched_barrier(0);
  float ivq[16];
#pragma unroll
  for (int r = 0; r < 16; ++r)
    ivq[r] = Ms[w * 32 + (r & 3) + 8 * (r >> 2) + 4 * hf];

#pragma unroll
  for (int dt = 0; dt < 2; ++dt) {
#pragma unroll
    for (int r = 0; r < 16; ++r) {
      int q = q0 + w * 32 + (r & 3) + 8 * (r >> 2) + 4 * hf;
      int d = h * HDIM + dt * 32 + l5;
      out[((size_t)b * SEQ + q) * DOUT + d] =
          (acc[dt][0][r] + acc[dt][1][r]) * ivq[r];
    }
  }
}

// ---------------------------------------------------------------------------
extern "C" void kernel_launch(void* const* d_in, const int* in_sizes, int n_in,
                              void* d_out, int out_size, void* d_ws,
                              size_t ws_size, hipStream_t stream) {
  const float* key = (const float*)d_in[0];
  const float* key_mask = (const float*)d_in[1];
  const float* query = (const float*)d_in[2];
  const float* value = (const float*)d_in[3];
  const float* wq = (const float*)d_in[4];
  const float* wk = (const float*)d_in[5];
  const float* wv = (const float*)d_in[6];
  float* out = (float*)d_out;

  char* ws = (char*)d_ws;
  f16* Qws = (f16*)(ws);              //  8.39 MB
  f16* Kws = (f16*)(ws + 8388608);    //  8.39 MB
  f16* Vtws = (f16*)(ws + 16777216);  //  8.39 MB
  f16* wT = (f16*)(ws + 25165824);    //  1.57 MB (total ~26.7 MB)

  prep_w<<<dim3(8, 8, 3), 256, 0, stream>>>(wq, wk, wv, wT);
  qkv_gemm<<<dim3(256, 1, 3), 256, 0, stream>>>(query, key, value, wT, Qws,
                                                Kws, Vtws);
  flash_attn<<<dim3(32, 16), 256, 0, stream>>>(Qws, Kws, Vtws, key_mask, out);
}

// Round 10
// 165.385 us; speedup vs baseline: 1.1593x; 1.0816x over previous
//
#include <hip/hip_runtime.h>

typedef _Float16 f16;
typedef f16 f16x8 __attribute__((ext_vector_type(8)));
typedef f16 f16x4 __attribute__((ext_vector_type(4)));
typedef f16 f16x2 __attribute__((ext_vector_type(2)));
typedef float f32x4 __attribute__((ext_vector_type(4)));
typedef float f32x16 __attribute__((ext_vector_type(16)));
typedef unsigned int u32;
typedef u32 u32x2 __attribute__((ext_vector_type(2)));
typedef u32 u32x4 __attribute__((ext_vector_type(4)));

#define MFMA16(a, b, c) __builtin_amdgcn_mfma_f32_16x16x32_f16(a, b, c, 0, 0, 0)
#define MFMA32(a, b, c) __builtin_amdgcn_mfma_f32_32x32x16_f16(a, b, c, 0, 0, 0)

#define BATCH 4
#define NHEADS 8
#define HDIM 64
#define SEQ 2048
#define DIN 512
#define DOUT 512
#define LOG2E 1.44269504f
#define C1 0.18033688f  // 0.125 * log2(e), folded into Q at qkv epilogue

__device__ __forceinline__ void gl_lds16(const void* g, const void* l) {
  __builtin_amdgcn_global_load_lds(
      (const __attribute__((address_space(1))) u32*)g,
      (__attribute__((address_space(3))) u32*)l, 16, 0, 0);
}

__device__ __forceinline__ float fexp2(float x) {
  float r;
  asm("v_exp_f32 %0, %1" : "=v"(r) : "v"(x));
  return r;
}

__device__ __forceinline__ u32 pk2u(float a, float b) {
  return __builtin_bit_cast(u32, __builtin_amdgcn_cvt_pkrtz(a, b));
}

__device__ __forceinline__ f16x2 pk2(float a, float b) {
  return __builtin_bit_cast(f16x2, __builtin_amdgcn_cvt_pkrtz(a, b));
}

__device__ __forceinline__ f16x4 pk4(float a, float b, float c, float d) {
  f16x2 u0 = pk2(a, b), u1 = pk2(c, d);
  f16x4 r;
  r[0] = u0[0]; r[1] = u0[1]; r[2] = u1[0]; r[3] = u1[1];
  return r;
}

// ---------------------------------------------------------------------------
// prep_w: transpose+cvt weights w[k][n] fp32 -> wT[n][k] f16.  (unchanged)
// ---------------------------------------------------------------------------
__global__ __launch_bounds__(256) void prep_w(
    const float* __restrict__ wq, const float* __restrict__ wk,
    const float* __restrict__ wv, f16* __restrict__ wT) {
  __shared__ float tile[64][65];
  const float* w = blockIdx.z == 0 ? wq : (blockIdx.z == 1 ? wk : wv);
  f16* out = wT + (size_t)blockIdx.z * DIN * DOUT;
  int k0 = blockIdx.x * 64, n0 = blockIdx.y * 64;
  int t = threadIdx.x;
  int c = t & 63, rb = t >> 6;
#pragma unroll
  for (int ph = 0; ph < 16; ++ph) {
    int r = ph * 4 + rb;
    tile[r][c] = w[(size_t)(k0 + r) * DOUT + n0 + c];
  }
  __syncthreads();
#pragma unroll
  for (int ph = 0; ph < 16; ++ph) {
    int n = ph * 4 + rb;
    out[(size_t)(n0 + n) * DIN + k0 + c] = (f16)tile[c][n];
  }
}

// ---------------------------------------------------------------------------
// qkv_gemm R17: software-pipelined A (1 k-step reg prefetch) + R16 B-dbuf.
//  - a_reg[8] holds tile t's A, loaded during iter t-1.  Packs at iter t
//    depend on LAST iter's loads -> no same-phase load->use chains.  The
//    pack's compiler vmcnt wait retires A(t) and (in-order) the older B(t)
//    DMAs, so no explicit vmcnt is needed before the barrier.
//  - occupancy 3->2 (__launch_bounds__(256,2)) buys the VGPR headroom for
//    the a_reg WAR renaming (R7/R15 spills were at occupancy 3's 170 cap).
//  - per iter: pack A(t); issue B(t+1) DMA; load A(t+1); lgkmcnt(0);
//    barrier; compute Bs[p]; barrier.  No vmcnt(0) drain in the loop.
//  - LDS 48 KB (As 16K + Bs dbuf 32K); CT aliases As+Bs0 (safe: writes
//    only after the final trailing barrier).
// ---------------------------------------------------------------------------
__global__ __launch_bounds__(256, 2) void qkv_gemm(
    const float* __restrict__ xq, const float* __restrict__ xk,
    const float* __restrict__ xv, const f16* __restrict__ wT,
    f16* __restrict__ Qo, f16* __restrict__ Ko, f16* __restrict__ Vt) {
  __shared__ __attribute__((aligned(16))) f16 smem[24576];  // 48 KB
  f16* As = smem;          // 128x64            (16 KB)
  f16* Bs = smem + 8192;   // 2 x 128x64 dbuf   (32 KB)
  f16* CT = smem;          // epilogue: 128x128 (aliases As+Bs0)

  int gemm = blockIdx.z;
  const float* x = gemm == 0 ? xq : (gemm == 1 ? xk : xv);
  const f16* wt = wT + (size_t)gemm * DIN * DOUT;
  int bx = blockIdx.x;
  int m0 = (bx & 63) * 128, n0 = (bx >> 6) * 128;
  int t = threadIdx.x, w = t >> 6, lane = t & 63;
  int lr = lane & 15, lq = lane >> 4;
  int wm = (w >> 1) * 64, wn = (w & 1) * 64;

  // A staging (fp32 -> f16 through regs): 16 threads/row, 8 row-phases.
  int tr = t >> 4, tc = t & 15;
  const float* xg = x + (size_t)(m0 + tr) * DIN + tc * 4;
  int aw[8];
#pragma unroll
  for (int ph = 0; ph < 8; ++ph) {
    int r = tr + 16 * ph;
    int phys = (tc >> 1) ^ (r & 7);
    aw[ph] = r * 64 + phys * 8 + (tc & 1) * 4;
  }

  // B staging via DMA: regions of 8 rows x 128B, XOR chunk swizzle.
  int srow = lane >> 3;
  int schunk = (lane & 7) ^ srow;
  const f16* gb[4];
  f16* lbb[4];
#pragma unroll
  for (int j = 0; j < 4; ++j) {
    int br = w * 32 + j * 8;
    gb[j] = wt + (size_t)(n0 + br + srow) * DIN + schunk * 8;
    lbb[j] = &Bs[__builtin_amdgcn_readfirstlane(br * 64)];
  }
  int xo0 = ((0 * 4 + lq) ^ (lr & 7)) * 8;
  int xo1 = ((1 * 4 + lq) ^ (lr & 7)) * 8;

  f32x4 zero = {0.f, 0.f, 0.f, 0.f};
  f32x4 acc[4][4];
#pragma unroll
  for (int i = 0; i < 4; ++i)
#pragma unroll
    for (int j = 0; j < 4; ++j) acc[i][j] = zero;

  // prologue: issue B(0) DMAs into Bs0; load A(0) into registers.
#pragma unroll
  for (int j = 0; j < 4; ++j) gl_lds16(gb[j], lbb[j]);
  float4 a_reg[8];
#pragma unroll
  for (int ph = 0; ph < 8; ++ph)
    a_reg[ph] = *(const float4*)(xg + (size_t)ph * 16 * DIN);

  for (int k0 = 0; k0 < DIN; k0 += 64) {
    int p = (k0 >> 6) & 1;
    // ---- pack A(t) from registers (the pack's vmcnt wait retires A(t)
    // and, by in-order retirement, the older B(t) DMAs).
#pragma unroll
    for (int ph = 0; ph < 8; ++ph)
      *(f16x4*)&As[aw[ph]] =
          pk4(a_reg[ph].x, a_reg[ph].y, a_reg[ph].z, a_reg[ph].w);
    // ---- issue B(t+1) into buf^1 (readers finished at trailing barrier
    // of iter t-1); then issue A(t+1) loads (land during compute + packs).
    if (k0 + 64 < DIN) {
#pragma unroll
      for (int j = 0; j < 4; ++j)
        gl_lds16(gb[j] + k0 + 64, lbb[j] + ((p ^ 1) * 8192));
#pragma unroll
      for (int ph = 0; ph < 8; ++ph)
        a_reg[ph] = *(const float4*)(xg + (size_t)ph * 16 * DIN + k0 + 64);
    }
    // ---- my A ds_writes visible; B(t) proven landed via pack waits.
    asm volatile("s_waitcnt lgkmcnt(0)" ::: "memory");
    __builtin_amdgcn_sched_barrier(0);
    __builtin_amdgcn_s_barrier();
    __builtin_amdgcn_sched_barrier(0);

    const f16* Bp = Bs + p * 8192;
#pragma unroll
    for (int c = 0; c < 2; ++c) {
      int xo = c ? xo1 : xo0;
      f16x8 xf[4], wf[4];
#pragma unroll
      for (int i = 0; i < 4; ++i)
        xf[i] = *(const f16x8*)&As[(wm + i * 16 + lr) * 64 + xo];
#pragma unroll
      for (int i = 0; i < 4; ++i)
        wf[i] = *(const f16x8*)&Bp[(wn + i * 16 + lr) * 64 + xo];
      if (gemm == 2) {
#pragma unroll
        for (int i = 0; i < 4; ++i)
#pragma unroll
          for (int j = 0; j < 4; ++j)
            acc[i][j] = MFMA16(xf[i], wf[j], acc[i][j]);
      } else {
#pragma unroll
        for (int i = 0; i < 4; ++i)
#pragma unroll
          for (int j = 0; j < 4; ++j)
            acc[i][j] = MFMA16(wf[i], xf[j], acc[i][j]);
      }
    }
    // reads of As/Bs[p] done before next iter's packs / epilogue CT.
    __builtin_amdgcn_sched_barrier(0);
    __builtin_amdgcn_s_barrier();
    __builtin_amdgcn_sched_barrier(0);
  }

  int b_ = m0 >> 11;
  int sl = m0 & 2047;

  if (gemm == 2) {
#pragma unroll
    for (int i = 0; i < 4; ++i) {
#pragma unroll
      for (int j = 0; j < 4; ++j) {
        int d = wn + j * 16 + lr;
        int lc = (wm >> 3) + i * 2 + (lq >> 1);
        int phys = lc ^ lr;
        *(f16x4*)&CT[d * 128 + phys * 8 + (lq & 1) * 4] =
            pk4(acc[i][j][0], acc[i][j][1], acc[i][j][2], acc[i][j][3]);
      }
    }
    __syncthreads();
    int tid16 = t & 15;
#pragma unroll
    for (int ph = 0; ph < 8; ++ph) {
      int d = ph * 16 + (t >> 4);
      int phys = tid16 ^ (d & 15);
      f16x8 vv = *(const f16x8*)&CT[d * 128 + phys * 8];
      int hgl = (n0 + d) >> 6, dd = (n0 + d) & 63;
      *(f16x8*)&Vt[(((size_t)b_ * NHEADS + hgl) * HDIM + dd) * SEQ + sl +
                   tid16 * 8] = vv;
    }
  } else {
    f16* O = gemm == 0 ? Qo : Ko;
    float sc = gemm == 0 ? C1 : 1.0f;
#pragma unroll
    for (int i = 0; i < 4; ++i) {
#pragma unroll
      for (int j = 0; j < 4; ++j) {
        int s = wm + j * 16 + lr;
        int lc = (wn >> 3) + i * 2 + (lq >> 1);
        int phys = lc ^ lr;
        *(f16x4*)&CT[s * 128 + phys * 8 + (lq & 1) * 4] =
            pk4(acc[i][j][0] * sc, acc[i][j][1] * sc, acc[i][j][2] * sc,
                acc[i][j][3] * sc);
      }
    }
    __syncthreads();
    int tid8 = t & 7;
    int hh = (t >> 3) & 1;
#pragma unroll
    for (int ph = 0; ph < 8; ++ph) {
      int s = ph * 16 + (t >> 4);
      int lc = hh * 8 + tid8;
      int phys = lc ^ (s & 15);
      f16x8 vv = *(const f16x8*)&CT[s * 128 + phys * 8];
      int hgl = (n0 >> 6) + hh;
      *(f16x8*)&O[(((size_t)b_ * NHEADS + hgl) * SEQ + sl + s) * HDIM +
                  tid8 * 8] = vv;
    }
  }
}

// ---------------------------------------------------------------------------
// flash_attn R14: FROZEN (control).
// ---------------------------------------------------------------------------
__global__ __launch_bounds__(256, 2) void flash_attn(
    const f16* __restrict__ Q, const f16* __restrict__ K,
    const f16* __restrict__ Vt, const float* __restrict__ mask,
    float* __restrict__ out) {
  __shared__ __attribute__((aligned(16))) f16 Ks[2 * 128 * 64];  // 32 KB
  __shared__ __attribute__((aligned(16))) f16 Vs[2 * 64 * 128];  // 32 KB
  __shared__ __attribute__((aligned(16))) float Ms[SEQ];         // 8 KB

  int bh = blockIdx.x, q0 = blockIdx.y * 128;
  int b = bh >> 3, h = bh & 7;
  int t = threadIdx.x, w = t >> 6, lane = t & 63;  // w in 0..3
  int l5 = lane & 31, hf = lane >> 5;

  const f16* Qg = Q + (size_t)bh * SEQ * HDIM;
  const f16* Kg = K + (size_t)bh * SEQ * HDIM;
  const f16* Vg = Vt + (size_t)bh * HDIM * SEQ;
  const float* mg = mask + (size_t)b * SEQ;

  // ---- staging pointers: K 4 regions of 8 rows x 128B; V 4 regions of 4x256B
  int krow = lane >> 3;
  int kchunk = (lane & 7) ^ krow;
  const f16* gk[4];
  const f16* gv[4];
  const f16* lk[4];
  const f16* lv[4];
#pragma unroll
  for (int j = 0; j < 4; ++j) {
    int kbr = w * 32 + j * 8;
    gk[j] = Kg + (size_t)(kbr + krow) * HDIM + kchunk * 8;
    lk[j] = &Ks[__builtin_amdgcn_readfirstlane(kbr * 64)];
    int vbr = w * 16 + j * 4;
    int lq = lane >> 4;
    int vchunk = (lane & 15) ^ ((vbr + lq) & 15);
    gv[j] = Vg + (size_t)(vbr + lq) * SEQ + vchunk * 8;
    lv[j] = &Vs[__builtin_amdgcn_readfirstlane(vbr * 128)];
  }

  // ---- prologue: stage mask + K0 + V0 into buf0 (DMA), then Q frags
  {
    int c0 = w * 512;  // 512 floats per wave, two 1KB DMAs
    gl_lds16(mg + c0 + lane * 4, &Ms[__builtin_amdgcn_readfirstlane(c0)]);
    gl_lds16(mg + c0 + 256 + lane * 4,
             &Ms[__builtin_amdgcn_readfirstlane(c0 + 256)]);
  }
#pragma unroll
  for (int j = 0; j < 4; ++j) {
    gl_lds16(gk[j], lk[j]);
    gl_lds16(gv[j], lv[j]);
  }

  // Q fragments (B-operand, rows q = q0 + w*32 + l5): qf[ds] covers
  // d = ds*16 + hf*8 + j
  f16x8 qf[4];
#pragma unroll
  for (int ds = 0; ds < 4; ++ds)
    qf[ds] = *(const f16x8*)(Qg + (size_t)(q0 + w * 32 + l5) * HDIM + ds * 16 +
                             hf * 8);

  const f32x16 Z = {0.f, 0.f, 0.f, 0.f, 0.f, 0.f, 0.f, 0.f,
                    0.f, 0.f, 0.f, 0.f, 0.f, 0.f, 0.f, 0.f};
  f32x16 acc[2][2];  // [dt][ks-parity] -> 4 independent MFMA chains
#pragma unroll
  for (int dt = 0; dt < 2; ++dt)
#pragma unroll
    for (int par = 0; par < 2; ++par) acc[dt][par] = Z;
  float lsum = 0.f;

  asm volatile("s_waitcnt vmcnt(0)" ::: "memory");
  __builtin_amdgcn_sched_barrier(0);
  __builtin_amdgcn_s_barrier();
  __builtin_amdgcn_sched_barrier(0);

#define QKT(nt, sv)                                                          \
  {                                                                          \
    __builtin_amdgcn_s_setprio(1);                                           \
    f16x8 kf0 = *(const f16x8*)&Kb[((nt)*32 + l5) * 64 +                     \
                                   (((0 + hf) ^ (l5 & 7)) * 8)];             \
    sv = MFMA32(kf0, qf[0], Z);                                              \
    _Pragma("unroll") for (int ds = 1; ds < 4; ++ds) {                       \
      f16x8 kf = *(const f16x8*)&Kb[((nt)*32 + l5) * 64 +                    \
                                    (((ds * 2 + hf) ^ (l5 & 7)) * 8)];       \
      sv = MFMA32(kf, qf[ds], sv);                                           \
    }                                                                        \
    __builtin_amdgcn_s_setprio(0);                                           \
  }

#define SM(nt, sv)                                                           \
  _Pragma("unroll") for (int run = 0; run < 4; ++run) {                      \
    float4 mk = *(const float4*)&Ms[k0 + (nt)*32 + run * 8 + 4 * hf];        \
    float p0 = fexp2(fmaf(mk.x, LOG2E, sv[run * 4 + 0]));                    \
    float p1 = fexp2(fmaf(mk.y, LOG2E, sv[run * 4 + 1]));                    \
    float p2 = fexp2(fmaf(mk.z, LOG2E, sv[run * 4 + 2]));                    \
    float p3 = fexp2(fmaf(mk.w, LOG2E, sv[run * 4 + 3]));                    \
    lsum += (p0 + p1) + (p2 + p3);                                           \
    pk_[nt][run][0] = pk2u(p0, p1);                                          \
    pk_[nt][run][1] = pk2u(p2, p3);                                          \
  }

  for (int it = 0; it < 16; ++it) {
    int p = it & 1;
    int k0 = it * 128;
    const f16* Kb = &Ks[p * 8192];
    const f16* Vb = &Vs[p * 8192];

    // ---- issue prefetch of tile t+1 into buf^1 (read-done via last barrier)
    if (it < 15) {
      int pn = p ^ 1;
#pragma unroll
      for (int j = 0; j < 4; ++j) {
        gl_lds16(gk[j] + (size_t)(k0 + 128) * HDIM, lk[j] + pn * 8192);
        gl_lds16(gv[j] + k0 + 128, lv[j] + pn * 8192);
      }
    }

    u32 pk_[4][4][2];  // [nt][g=r>>2][word]

    // ---- S^T = K Q^T with nt-skew: QKT(nt+1) issued before softmax(nt)
    {
      f32x16 sA, sB;
      QKT(0, sA);
      QKT(1, sB);
      SM(0, sA);
      QKT(2, sA);
      SM(1, sB);
      QKT(3, sB);
      SM(2, sA);
      SM(3, sB);
    }

    // ---- O += P V  (ap assembled in-register via permlane32_swap);
    //      acc chains split by ks parity (4 independent chains)
    __builtin_amdgcn_s_setprio(1);
#pragma unroll
    for (int ks = 0; ks < 8; ++ks) {
      const int nt = ks >> 1;
      const int ge = 2 * (ks & 1);      // g for hf=0 lanes
      const int go = 2 * (ks & 1) + 1;  // g for hf=1 lanes
      u32x2 r0 = __builtin_amdgcn_permlane32_swap(pk_[nt][ge][0],
                                                  pk_[nt][go][0], false, false);
      u32x2 r1 = __builtin_amdgcn_permlane32_swap(pk_[nt][ge][1],
                                                  pk_[nt][go][1], false, false);
      u32x4 apw = {r0[0], r1[0], r0[1], r1[1]};
      f16x8 ap = __builtin_bit_cast(f16x8, apw);
#pragma unroll
      for (int dt = 0; dt < 2; ++dt) {
        f16x8 bv = *(const f16x8*)&Vb[(dt * 32 + l5) * 128 +
                                      (((ks * 2 + hf) ^ (l5 & 15)) * 8)];
        acc[dt][ks & 1] = MFMA32(ap, bv, acc[dt][ks & 1]);
      }
    }
    __builtin_amdgcn_s_setprio(0);

    // ---- single end-of-iter sync: own DMAs (issued at iter start) landed;
    // barrier => all waves' DMAs landed + all reads of buf done.
    asm volatile("s_waitcnt vmcnt(0)" ::: "memory");
    __builtin_amdgcn_sched_barrier(0);
    __builtin_amdgcn_s_barrier();
    __builtin_amdgcn_sched_barrier(0);
  }
#undef QKT
#undef SM

  // ---- epilogue: cross-half l sum, redistribute inv via Ms[0:128) scratch
  // (safe: last-iter mask reads touch Ms[1920:2048) only; region is
  // wave-private so no barrier needed)
  float l = lsum + __shfl_xor(lsum, 32);
  float inv = 1.f / l;
  Ms[w * 32 + l5] = inv;  // lanes l5 / l5+32 write same value
  asm volatile("s_waitcnt lgkmcnt(0)" ::: "memory");
  __builtin_amdgcn_sched_barrier(0);
  float ivq[16];
#pragma unroll
  for (int r = 0; r < 16; ++r)
    ivq[r] = Ms[w * 32 + (r & 3) + 8 * (r >> 2) + 4 * hf];

#pragma unroll
  for (int dt = 0; dt < 2; ++dt) {
#pragma unroll
    for (int r = 0; r < 16; ++r) {
      int q = q0 + w * 32 + (r & 3) + 8 * (r >> 2) + 4 * hf;
      int d = h * HDIM + dt * 32 + l5;
      out[((size_t)b * SEQ + q) * DOUT + d] =
          (acc[dt][0][r] + acc[dt][1][r]) * ivq[r];
    }
  }
}

// ---------------------------------------------------------------------------
extern "C" void kernel_launch(void* const* d_in, const int* in_sizes, int n_in,
                              void* d_out, int out_size, void* d_ws,
                              size_t ws_size, hipStream_t stream) {
  const float* key = (const float*)d_in[0];
  const float* key_mask = (const float*)d_in[1];
  const float* query = (const float*)d_in[2];
  const float* value = (const float*)d_in[3];
  const float* wq = (const float*)d_in[4];
  const float* wk = (const float*)d_in[5];
  const float* wv = (const float*)d_in[6];
  float* out = (float*)d_out;

  char* ws = (char*)d_ws;
  f16* Qws = (f16*)(ws);              //  8.39 MB
  f16* Kws = (f16*)(ws + 8388608);    //  8.39 MB
  f16* Vtws = (f16*)(ws + 16777216);  //  8.39 MB
  f16* wT = (f16*)(ws + 25165824);    //  1.57 MB (total ~26.7 MB)

  prep_w<<<dim3(8, 8, 3), 256, 0, stream>>>(wq, wk, wv, wT);
  qkv_gemm<<<dim3(256, 1, 3), 256, 0, stream>>>(query, key, value, wT, Qws,
                                                Kws, Vtws);
  flash_attn<<<dim3(32, 16), 256, 0, stream>>>(Qws, Kws, Vtws, key_mask, out);
}